// Round 3
// baseline (2573.552 us; speedup 1.0000x reference)
//
#include <hip/hip_runtime.h>
#include <cmath>

// Problem constants (match reference)
#define N_NODES 16384
#define E_EDGES 262144
#define HD 128
#define NLAYER 4

__device__ __forceinline__ float silu_f(float x) { return x / (1.0f + expf(-x)); }

// ---------------------------------------------------------------------------
// Generic fp32 GEMM: C[M,128] = act(A[M,K] @ W[K,128] + bias)
// BM=64, BN=128 (full), BK=32, 256 threads, per-thread 4 rows x 8 cols.
// ACT: 0 = none, 1 = silu
// Used only for the (tiny) injector MLP layers 2 and 3.
// ---------------------------------------------------------------------------
template <int ACT>
__global__ __launch_bounds__(256, 2) void k_gemm128(const float* Ag, const float* __restrict__ W,
                                                    const float* __restrict__ bias, float* C, int K) {
  __shared__ float As[64][33];
  __shared__ float Ws[32][128];
  const int tid = threadIdx.x;
  const int tc = tid & 15, tr = tid >> 4;
  const int tr4 = tr * 4, tc4 = tc * 4;
  const int m0 = blockIdx.x * 64;

  float acc[4][8];
#pragma unroll
  for (int i = 0; i < 4; ++i)
#pragma unroll
    for (int j = 0; j < 8; ++j) acc[i][j] = 0.0f;

  for (int kk = 0; kk < K; kk += 32) {
    int idx = tid;
#pragma unroll
    for (int it = 0; it < 2; ++it, idx += 256) {
      int r = idx >> 3, c4 = (idx & 7) << 2;
      float4 v = *(const float4*)(Ag + (size_t)(m0 + r) * K + kk + c4);
      As[r][c4] = v.x; As[r][c4 + 1] = v.y; As[r][c4 + 2] = v.z; As[r][c4 + 3] = v.w;
    }
    idx = tid;
#pragma unroll
    for (int it = 0; it < 4; ++it, idx += 256) {
      int r = idx >> 5, c4 = (idx & 31) << 2;
      *(float4*)(&Ws[r][c4]) = *(const float4*)(W + (size_t)(kk + r) * 128 + c4);
    }
    __syncthreads();
#pragma unroll
    for (int k = 0; k < 32; ++k) {
      float av[4];
#pragma unroll
      for (int i = 0; i < 4; ++i) av[i] = As[tr4 + i][k];
      float4 b0 = *(const float4*)(&Ws[k][tc4]);
      float4 b1 = *(const float4*)(&Ws[k][64 + tc4]);
      float bv[8] = {b0.x, b0.y, b0.z, b0.w, b1.x, b1.y, b1.z, b1.w};
#pragma unroll
      for (int i = 0; i < 4; ++i)
#pragma unroll
        for (int j = 0; j < 8; ++j) acc[i][j] = fmaf(av[i], bv[j], acc[i][j]);
    }
    __syncthreads();
  }

  float bv0[8];
#pragma unroll
  for (int j = 0; j < 4; ++j) { bv0[j] = bias[tc4 + j]; bv0[4 + j] = bias[64 + tc4 + j]; }
#pragma unroll
  for (int i = 0; i < 4; ++i) {
    size_t row = m0 + tr4 + i;
    float o[8];
#pragma unroll
    for (int j = 0; j < 8; ++j) {
      float v = acc[i][j] + bv0[j];
      if (ACT >= 1) v = silu_f(v);
      o[j] = v;
    }
    *(float4*)(C + row * 128 + tc4) = make_float4(o[0], o[1], o[2], o[3]);
    *(float4*)(C + row * 128 + 64 + tc4) = make_float4(o[4], o[5], o[6], o[7]);
  }
}

// ---------------------------------------------------------------------------
// FUSED edge pipeline, one kernel per 64 CSR-sorted edges:
//   m1 = silu(cat(h[row], h[col], dsq) @ eW1 + eb1)         (K=257, LDS T_t)
//   m2 = clip(silu(m1 @ eW2 + eb2), -10, 10)                (-> global m_s, T_t)
//   cw = silu(m2 @ cW1 + cb1) @ cW2                         (-> global cw_s)
// A-operand tiles are stored K-MAJOR in LDS (As_t[k][row], T_t[k][row]) so the
// inner-loop A-fragment read is one aligned ds_read_b128 (4 distinct addrs per
// wave -> broadcast) instead of 4 ds_read_b32 column reads. Static LDS-pipe
// cycles per k-step drop ~47 -> ~36 (reads), relieving the CU-shared LDS pipe
// which the cycle model says was ~3x oversubscribed vs VALU.
// Edges processed in perm (CSR) order so m_s/rel_s/cw_s are contiguous per
// destination node. T_t (128x68) is reused across stages; As_t aliases T_t.
// LDS ~52.5 KB -> 2-3 blocks/CU.
// ---------------------------------------------------------------------------
__global__ __launch_bounds__(256, 2) void k_edge_fused(
    const float* __restrict__ h, const float* __restrict__ pos,
    const int* __restrict__ rows, const int* __restrict__ cols,
    const int* __restrict__ perm,
    const float* __restrict__ eW1, const float* __restrict__ eb1,
    const float* __restrict__ eW2, const float* __restrict__ eb2,
    const float* __restrict__ cW1, const float* __restrict__ cb1,
    const float* __restrict__ cW2,
    float* __restrict__ m_s, float* __restrict__ rel_s, float* __restrict__ cw_s) {
  __shared__ float T[128][68];   // k-major activations; first 32 rows double as As_t
  __shared__ float Ws[32][128];
  __shared__ int srow[64], scol[64];
  __shared__ float sdsq[64];
  __shared__ float sW2[128];
  float(*As_t)[68] = T;  // alias: As_t[32][68] within T's storage

  const int tid = threadIdx.x;
  const int tc = tid & 15, tr = tid >> 4;
  const int tr4 = tr * 4, tc4 = tc * 4;
  const int j0 = blockIdx.x * 64;

  if (tid < 64) {
    int e = perm[j0 + tid];
    int r = rows[e], c = cols[e];
    srow[tid] = r; scol[tid] = c;
    float rx = pos[r * 3 + 0] - pos[c * 3 + 0];
    float ry = pos[r * 3 + 1] - pos[c * 3 + 1];
    float rz = pos[r * 3 + 2] - pos[c * 3 + 2];
    rel_s[(size_t)(j0 + tid) * 3 + 0] = rx;
    rel_s[(size_t)(j0 + tid) * 3 + 1] = ry;
    rel_s[(size_t)(j0 + tid) * 3 + 2] = rz;
    float d = rx * rx + ry * ry + rz * rz;
    sdsq[tid] = fminf(fmaxf(d, 1e-6f), 1e6f);
  }
  if (tid < 128) sW2[tid] = cW2[tid];
  __syncthreads();

  // ---- stage 1: cat(h[row], h[col]) @ eW1, K = 256 staged + dsq term ----
  float acc[4][8];
#pragma unroll
  for (int i = 0; i < 4; ++i)
#pragma unroll
    for (int j = 0; j < 8; ++j) acc[i][j] = 0.0f;

  for (int kk = 0; kk < 256; kk += 32) {
    int idx = tid;
#pragma unroll
    for (int it = 0; it < 2; ++it, idx += 256) {
      int r = idx >> 3, c4 = (idx & 7) << 2;
      int node = (kk < 128) ? srow[r] : scol[r];
      float4 v = *(const float4*)(h + (size_t)node * 128 + (kk & 127) + c4);
      As_t[c4 + 0][r] = v.x; As_t[c4 + 1][r] = v.y;
      As_t[c4 + 2][r] = v.z; As_t[c4 + 3][r] = v.w;
    }
    idx = tid;
#pragma unroll
    for (int it = 0; it < 4; ++it, idx += 256) {
      int r = idx >> 5, c4 = (idx & 31) << 2;
      *(float4*)(&Ws[r][c4]) = *(const float4*)(eW1 + (size_t)(kk + r) * 128 + c4);
    }
    __syncthreads();
#pragma unroll
    for (int k = 0; k < 32; ++k) {
      float4 a4 = *(const float4*)(&As_t[k][tr4]);
      float av[4] = {a4.x, a4.y, a4.z, a4.w};
      float4 b0 = *(const float4*)(&Ws[k][tc4]);
      float4 b1v = *(const float4*)(&Ws[k][64 + tc4]);
      float bv[8] = {b0.x, b0.y, b0.z, b0.w, b1v.x, b1v.y, b1v.z, b1v.w};
#pragma unroll
      for (int i = 0; i < 4; ++i)
#pragma unroll
        for (int j = 0; j < 8; ++j) acc[i][j] = fmaf(av[i], bv[j], acc[i][j]);
    }
    __syncthreads();
  }

  // k=256 (dsq) term + bias + silu -> T_t (k-major: T_t[col][edge_row])
  {
    float wl[8], bb[8];
#pragma unroll
    for (int j = 0; j < 4; ++j) {
      wl[j] = eW1[256 * 128 + tc4 + j];
      wl[4 + j] = eW1[256 * 128 + 64 + tc4 + j];
      bb[j] = eb1[tc4 + j];
      bb[4 + j] = eb1[64 + tc4 + j];
    }
#pragma unroll
    for (int i = 0; i < 4; ++i) {
      float d = sdsq[tr4 + i];
#pragma unroll
      for (int j = 0; j < 4; ++j) {
        T[tc4 + j][tr4 + i] = silu_f(acc[i][j] + d * wl[j] + bb[j]);
        T[64 + tc4 + j][tr4 + i] = silu_f(acc[i][4 + j] + d * wl[4 + j] + bb[4 + j]);
      }
    }
  }
  __syncthreads();

  // ---- stage 2: m2 = clip(silu(T @ eW2 + eb2)) ----
#pragma unroll
  for (int i = 0; i < 4; ++i)
#pragma unroll
    for (int j = 0; j < 8; ++j) acc[i][j] = 0.0f;
  for (int kk = 0; kk < 128; kk += 32) {
    int idx = tid;
#pragma unroll
    for (int it = 0; it < 4; ++it, idx += 256) {
      int r = idx >> 5, c4 = (idx & 31) << 2;
      *(float4*)(&Ws[r][c4]) = *(const float4*)(eW2 + (size_t)(kk + r) * 128 + c4);
    }
    __syncthreads();
#pragma unroll
    for (int k = 0; k < 32; ++k) {
      float4 a4 = *(const float4*)(&T[kk + k][tr4]);
      float av[4] = {a4.x, a4.y, a4.z, a4.w};
      float4 b0 = *(const float4*)(&Ws[k][tc4]);
      float4 b1v = *(const float4*)(&Ws[k][64 + tc4]);
      float bv[8] = {b0.x, b0.y, b0.z, b0.w, b1v.x, b1v.y, b1v.z, b1v.w};
#pragma unroll
      for (int i = 0; i < 4; ++i)
#pragma unroll
        for (int j = 0; j < 8; ++j) acc[i][j] = fmaf(av[i], bv[j], acc[i][j]);
    }
    __syncthreads();
  }
  // epilogue: bias+silu+clip -> global m_s and back into T_t
  {
    float bb[8];
#pragma unroll
    for (int j = 0; j < 4; ++j) { bb[j] = eb2[tc4 + j]; bb[4 + j] = eb2[64 + tc4 + j]; }
    float o[4][8];
#pragma unroll
    for (int i = 0; i < 4; ++i) {
      size_t row = j0 + tr4 + i;
#pragma unroll
      for (int j = 0; j < 8; ++j) {
        float v = silu_f(acc[i][j] + bb[j]);
        o[i][j] = fminf(fmaxf(v, -10.0f), 10.0f);
      }
      *(float4*)(m_s + row * 128 + tc4) = make_float4(o[i][0], o[i][1], o[i][2], o[i][3]);
      *(float4*)(m_s + row * 128 + 64 + tc4) = make_float4(o[i][4], o[i][5], o[i][6], o[i][7]);
    }
    // all threads are past the stage-2 k-loop barrier; safe to overwrite T
#pragma unroll
    for (int i = 0; i < 4; ++i) {
#pragma unroll
      for (int j = 0; j < 4; ++j) {
        T[tc4 + j][tr4 + i] = o[i][j];
        T[64 + tc4 + j][tr4 + i] = o[i][4 + j];
      }
    }
  }
  __syncthreads();

  // ---- stage 3: cw = silu(T @ cW1 + cb1) . cW2 ----
#pragma unroll
  for (int i = 0; i < 4; ++i)
#pragma unroll
    for (int j = 0; j < 8; ++j) acc[i][j] = 0.0f;
  for (int kk = 0; kk < 128; kk += 32) {
    int idx = tid;
#pragma unroll
    for (int it = 0; it < 4; ++it, idx += 256) {
      int r = idx >> 5, c4 = (idx & 31) << 2;
      *(float4*)(&Ws[r][c4]) = *(const float4*)(cW1 + (size_t)(kk + r) * 128 + c4);
    }
    __syncthreads();
#pragma unroll
    for (int k = 0; k < 32; ++k) {
      float4 a4 = *(const float4*)(&T[kk + k][tr4]);
      float av[4] = {a4.x, a4.y, a4.z, a4.w};
      float4 b0 = *(const float4*)(&Ws[k][tc4]);
      float4 b1v = *(const float4*)(&Ws[k][64 + tc4]);
      float bv[8] = {b0.x, b0.y, b0.z, b0.w, b1v.x, b1v.y, b1v.z, b1v.w};
#pragma unroll
      for (int i = 0; i < 4; ++i)
#pragma unroll
        for (int j = 0; j < 8; ++j) acc[i][j] = fmaf(av[i], bv[j], acc[i][j]);
    }
    __syncthreads();
  }
  {
    float p[4] = {0.f, 0.f, 0.f, 0.f};
#pragma unroll
    for (int i = 0; i < 4; ++i) {
#pragma unroll
      for (int j = 0; j < 4; ++j) {
        p[i] += silu_f(acc[i][j] + cb1[tc4 + j]) * sW2[tc4 + j];
        p[i] += silu_f(acc[i][4 + j] + cb1[64 + tc4 + j]) * sW2[64 + tc4 + j];
      }
    }
#pragma unroll
    for (int d = 1; d < 16; d <<= 1) {
#pragma unroll
      for (int i = 0; i < 4; ++i) p[i] += __shfl_xor(p[i], d);
    }
    if (tc == 0) {
#pragma unroll
      for (int i = 0; i < 4; ++i) cw_s[j0 + tr4 + i] = p[i];
    }
  }
}

// ---------------------------------------------------------------------------
// CSR build: count -> scan -> fill permutation
// ---------------------------------------------------------------------------
__global__ void k_count(const int* __restrict__ rows, int* __restrict__ cnt) {
  int e = blockIdx.x * 256 + threadIdx.x;
  if (e < E_EDGES) atomicAdd(&cnt[rows[e]], 1);
}

__global__ void k_scan(const int* __restrict__ cnt, int* __restrict__ offs) {
  __shared__ int part[256];
  const int tid = threadIdx.x;
  const int base = tid * 64;
  int s = 0;
  for (int i = 0; i < 64; ++i) s += cnt[base + i];
  part[tid] = s;
  __syncthreads();
  for (int d = 1; d < 256; d <<= 1) {
    int v = (tid >= d) ? part[tid - d] : 0;
    __syncthreads();
    part[tid] += v;
    __syncthreads();
  }
  int run = part[tid] - s;  // exclusive prefix of this chunk
  for (int i = 0; i < 64; ++i) { offs[base + i] = run; run += cnt[base + i]; }
  if (tid == 255) offs[N_NODES] = run;  // == E
}

__global__ void k_fill(const int* __restrict__ rows, const int* __restrict__ offs,
                       int* __restrict__ fill, int* __restrict__ perm) {
  int e = blockIdx.x * 256 + threadIdx.x;
  if (e < E_EDGES) {
    int r = rows[e];
    int p = atomicAdd(&fill[r], 1);
    perm[offs[r] + p] = e;
  }
}

// ---------------------------------------------------------------------------
// Per-node gather over the CSR-contiguous sorted buffers:
//   agg[n,:] = sum_j m_s[j,:] ; pos[n,:] += sum_j(cw_s[j]*rel_s[j,:]) / deg
// 2 nodes per block, 128 threads (one column) each. All reads streaming.
// ---------------------------------------------------------------------------
__global__ void k_node_gather(const float* __restrict__ m_s, const float* __restrict__ cw_s,
                              const float* __restrict__ rel_s, const int* __restrict__ offs,
                              float* __restrict__ agg, float* __restrict__ pos) {
  const int node = blockIdx.x * 2 + (threadIdx.x >> 7);
  const int c = threadIdx.x & 127;
  const int o0 = offs[node], o1 = offs[node + 1];
  float s = 0.0f;
  for (int j = o0; j < o1; ++j) s += m_s[(size_t)j * 128 + c];
  agg[(size_t)node * 128 + c] = s;
  if (c < 3) {
    float cu = 0.0f;
    for (int j = o0; j < o1; ++j) cu += cw_s[j] * rel_s[(size_t)j * 3 + c];
    float deg = (float)(o1 - o0);
    pos[node * 3 + c] += cu / (deg + 1e-6f);
  }
}

// ---------------------------------------------------------------------------
// Node MLP + residual + LayerNorm (fused, in-place on h):
// h = LN(h + silu(cat(h,agg)@W1+b1)@W2 + b2) * g + b
// ---------------------------------------------------------------------------
__global__ __launch_bounds__(256, 2) void k_node_mlp(float* __restrict__ h, const float* __restrict__ agg,
                                                     const float* __restrict__ W1, const float* __restrict__ b1,
                                                     const float* __restrict__ W2, const float* __restrict__ b2,
                                                     const float* __restrict__ lng, const float* __restrict__ lnb) {
  __shared__ float As[64][33];
  __shared__ float Ws[32][128];
  __shared__ float T[64][132];
  const int tid = threadIdx.x;
  const int tc = tid & 15, tr = tid >> 4;
  const int tr4 = tr * 4, tc4 = tc * 4;
  const int m0 = blockIdx.x * 64;

  float acc[4][8];
#pragma unroll
  for (int i = 0; i < 4; ++i)
#pragma unroll
    for (int j = 0; j < 8; ++j) acc[i][j] = 0.0f;

  // phase A: t1 = silu(cat(h,agg) @ W1 + b1), K = 256
  for (int kk = 0; kk < 256; kk += 32) {
    const float* src = (kk < 128) ? h : agg;
    const int kb = kk & 127;
    int idx = tid;
#pragma unroll
    for (int it = 0; it < 2; ++it, idx += 256) {
      int r = idx >> 3, c4 = (idx & 7) << 2;
      float4 v = *(const float4*)(src + (size_t)(m0 + r) * 128 + kb + c4);
      As[r][c4] = v.x; As[r][c4 + 1] = v.y; As[r][c4 + 2] = v.z; As[r][c4 + 3] = v.w;
    }
    idx = tid;
#pragma unroll
    for (int it = 0; it < 4; ++it, idx += 256) {
      int r = idx >> 5, c4 = (idx & 31) << 2;
      *(float4*)(&Ws[r][c4]) = *(const float4*)(W1 + (size_t)(kk + r) * 128 + c4);
    }
    __syncthreads();
#pragma unroll
    for (int k = 0; k < 32; ++k) {
      float av[4];
#pragma unroll
      for (int i = 0; i < 4; ++i) av[i] = As[tr4 + i][k];
      float4 b0 = *(const float4*)(&Ws[k][tc4]);
      float4 b1v = *(const float4*)(&Ws[k][64 + tc4]);
      float bv[8] = {b0.x, b0.y, b0.z, b0.w, b1v.x, b1v.y, b1v.z, b1v.w};
#pragma unroll
      for (int i = 0; i < 4; ++i)
#pragma unroll
        for (int j = 0; j < 8; ++j) acc[i][j] = fmaf(av[i], bv[j], acc[i][j]);
    }
    __syncthreads();
  }
#pragma unroll
  for (int i = 0; i < 4; ++i) {
#pragma unroll
    for (int j = 0; j < 4; ++j) {
      T[tr4 + i][tc4 + j] = silu_f(acc[i][j] + b1[tc4 + j]);
      T[tr4 + i][64 + tc4 + j] = silu_f(acc[i][4 + j] + b1[64 + tc4 + j]);
    }
  }
  __syncthreads();

  // phase B: nu = T @ W2, K = 128
  float acc2[4][8];
#pragma unroll
  for (int i = 0; i < 4; ++i)
#pragma unroll
    for (int j = 0; j < 8; ++j) acc2[i][j] = 0.0f;
  for (int kk = 0; kk < 128; kk += 32) {
    int idx = tid;
#pragma unroll
    for (int it = 0; it < 4; ++it, idx += 256) {
      int r = idx >> 5, c4 = (idx & 31) << 2;
      *(float4*)(&Ws[r][c4]) = *(const float4*)(W2 + (size_t)(kk + r) * 128 + c4);
    }
    __syncthreads();
#pragma unroll
    for (int k = 0; k < 32; ++k) {
      float av[4];
#pragma unroll
      for (int i = 0; i < 4; ++i) av[i] = T[tr4 + i][kk + k];
      float4 b0 = *(const float4*)(&Ws[k][tc4]);
      float4 b1v = *(const float4*)(&Ws[k][64 + tc4]);
      float bv[8] = {b0.x, b0.y, b0.z, b0.w, b1v.x, b1v.y, b1v.z, b1v.w};
#pragma unroll
      for (int i = 0; i < 4; ++i)
#pragma unroll
        for (int j = 0; j < 8; ++j) acc2[i][j] = fmaf(av[i], bv[j], acc2[i][j]);
    }
    __syncthreads();
  }

  // epilogue: x = h + nu + b2 ; LayerNorm over 128 cols (16 lanes share a row)
  float x[4][8], s1[4], s2[4];
#pragma unroll
  for (int i = 0; i < 4; ++i) {
    size_t row = m0 + tr4 + i;
    float4 h0 = *(const float4*)(h + row * 128 + tc4);
    float4 h1 = *(const float4*)(h + row * 128 + 64 + tc4);
    float hv[8] = {h0.x, h0.y, h0.z, h0.w, h1.x, h1.y, h1.z, h1.w};
    s1[i] = 0.f; s2[i] = 0.f;
#pragma unroll
    for (int j = 0; j < 8; ++j) {
      int cidx = (j < 4) ? (tc4 + j) : (64 + tc4 + (j - 4));
      float v = hv[j] + acc2[i][j] + b2[cidx];
      x[i][j] = v;
      s1[i] += v;
      s2[i] += v * v;
    }
  }
#pragma unroll
  for (int d = 1; d < 16; d <<= 1) {
#pragma unroll
    for (int i = 0; i < 4; ++i) {
      s1[i] += __shfl_xor(s1[i], d);
      s2[i] += __shfl_xor(s2[i], d);
    }
  }
  float gv[8], bv[8];
#pragma unroll
  for (int j = 0; j < 4; ++j) {
    gv[j] = lng[tc4 + j]; gv[4 + j] = lng[64 + tc4 + j];
    bv[j] = lnb[tc4 + j]; bv[4 + j] = lnb[64 + tc4 + j];
  }
#pragma unroll
  for (int i = 0; i < 4; ++i) {
    float mu = s1[i] * (1.0f / 128.0f);
    float var = s2[i] * (1.0f / 128.0f) - mu * mu;
    float rs = rsqrtf(var + 1e-5f);
    size_t row = m0 + tr4 + i;
    float o[8];
#pragma unroll
    for (int j = 0; j < 8; ++j) o[j] = (x[i][j] - mu) * rs * gv[j] + bv[j];
    *(float4*)(h + row * 128 + tc4) = make_float4(o[0], o[1], o[2], o[3]);
    *(float4*)(h + row * 128 + 64 + tc4) = make_float4(o[4], o[5], o[6], o[7]);
  }
}

// ---------------------------------------------------------------------------
// Injector layer 1: out[N,256] = silu(cat(atom_types, z[n/64]) @ W1 + b1)
// K=80 (single stage). grid = (2 col tiles, N/64 row tiles)
// ---------------------------------------------------------------------------
__global__ __launch_bounds__(256) void k_inj1(const float* __restrict__ at, const float* __restrict__ z,
                                              const float* __restrict__ W1, const float* __restrict__ b1,
                                              float* __restrict__ out) {
  __shared__ float As[64][84];
  __shared__ float Ws[80][128];
  const int tid = threadIdx.x;
  const int tc = tid & 15, tr = tid >> 4;
  const int tr4 = tr * 4, tc4 = tc * 4;
  const int m0 = blockIdx.y * 64;
  const int cb = blockIdx.x * 128;

  int idx = tid;
#pragma unroll
  for (int it = 0; it < 5; ++it, idx += 256) {
    int r = idx / 20, c4 = idx % 20;
    int n = m0 + r;
    float4 v;
    if (c4 < 4) v = *(const float4*)(at + (size_t)n * 16 + c4 * 4);
    else v = *(const float4*)(z + (size_t)(n >> 6) * 64 + (c4 - 4) * 4);
    *(float4*)(&As[r][c4 * 4]) = v;
  }
  idx = tid;
#pragma unroll
  for (int it = 0; it < 10; ++it, idx += 256) {
    int r = idx >> 5, c4 = (idx & 31) << 2;
    *(float4*)(&Ws[r][c4]) = *(const float4*)(W1 + (size_t)r * 256 + cb + c4);
  }
  __syncthreads();

  float acc[4][8];
#pragma unroll
  for (int i = 0; i < 4; ++i)
#pragma unroll
    for (int j = 0; j < 8; ++j) acc[i][j] = 0.0f;
#pragma unroll 4
  for (int k = 0; k < 80; ++k) {
    float av[4];
#pragma unroll
    for (int i = 0; i < 4; ++i) av[i] = As[tr4 + i][k];
    float4 b0 = *(const float4*)(&Ws[k][tc4]);
    float4 b1v = *(const float4*)(&Ws[k][64 + tc4]);
    float bv[8] = {b0.x, b0.y, b0.z, b0.w, b1v.x, b1v.y, b1v.z, b1v.w};
#pragma unroll
    for (int i = 0; i < 4; ++i)
#pragma unroll
      for (int j = 0; j < 8; ++j) acc[i][j] = fmaf(av[i], bv[j], acc[i][j]);
  }

  float bb[8];
#pragma unroll
  for (int j = 0; j < 4; ++j) { bb[j] = b1[cb + tc4 + j]; bb[4 + j] = b1[cb + 64 + tc4 + j]; }
#pragma unroll
  for (int i = 0; i < 4; ++i) {
    size_t row = m0 + tr4 + i;
    float o[8];
#pragma unroll
    for (int j = 0; j < 8; ++j) o[j] = silu_f(acc[i][j] + bb[j]);
    *(float4*)(out + row * 256 + cb + tc4) = make_float4(o[0], o[1], o[2], o[3]);
    *(float4*)(out + row * 256 + cb + 64 + tc4) = make_float4(o[4], o[5], o[6], o[7]);
  }
}

__global__ void k_copyf(const float* __restrict__ in, float* __restrict__ out, int n) {
  int i = blockIdx.x * 256 + threadIdx.x;
  if (i < n) out[i] = in[i];
}

// ---------------------------------------------------------------------------
extern "C" void kernel_launch(void* const* d_in, const int* in_sizes, int n_in,
                              void* d_out, int out_size, void* d_ws, size_t ws_size,
                              hipStream_t stream) {
  const float* z = (const float*)d_in[0];
  const float* at = (const float*)d_in[1];
  const float* pos0 = (const float*)d_in[2];
  const int* ei = (const int*)d_in[3];
  const float* injW1 = (const float*)d_in[4];
  const float* injb1 = (const float*)d_in[5];
  const float* injW2 = (const float*)d_in[6];
  const float* injb2 = (const float*)d_in[7];
  const float* injW3 = (const float*)d_in[8];
  const float* injb3 = (const float*)d_in[9];
  const float* eW1 = (const float*)d_in[10];
  const float* eb1 = (const float*)d_in[11];
  const float* eW2 = (const float*)d_in[12];
  const float* eb2 = (const float*)d_in[13];
  const float* cW1 = (const float*)d_in[14];
  const float* cb1 = (const float*)d_in[15];
  const float* cW2 = (const float*)d_in[16];
  const float* nW1 = (const float*)d_in[17];
  const float* nb1 = (const float*)d_in[18];
  const float* nW2 = (const float*)d_in[19];
  const float* nb2 = (const float*)d_in[20];
  const float* lng = (const float*)d_in[21];
  const float* lnb = (const float*)d_in[22];

  float* w = (float*)d_ws;
  float* h = w;    w += (size_t)N_NODES * HD;   // 2M floats
  float* pos = w;  w += (size_t)N_NODES * 3;
  float* m_s = w;  w += (size_t)E_EDGES * HD;   // 33.5M floats (CSR-sorted)
  float* rel_s = w; w += (size_t)E_EDGES * 3;
  float* cw_s = w; w += (size_t)E_EDGES;
  float* agg = w;  w += (size_t)N_NODES * HD;
  float* t1 = m_s;  // alias: m_s unused during injection, t1 is [N,256]
  float* t2 = agg;  // alias: agg unused during injection, t2 is [N,128]
  int* ib = (int*)w;
  int* cnt = ib;  ib += N_NODES;
  int* offs = ib; ib += N_NODES + 1;
  int* fill = ib; ib += N_NODES;
  int* perm = ib; ib += E_EDGES;

  const int* rowsp = ei;
  const int* colsp = ei + E_EDGES;

  // CSR build (graph is static per call but must be rebuilt each call)
  hipMemsetAsync(cnt, 0, N_NODES * sizeof(int), stream);
  hipMemsetAsync(fill, 0, N_NODES * sizeof(int), stream);
  k_count<<<E_EDGES / 256, 256, 0, stream>>>(rowsp, cnt);
  k_scan<<<1, 256, 0, stream>>>(cnt, offs);
  k_fill<<<E_EDGES / 256, 256, 0, stream>>>(rowsp, offs, fill, perm);
  k_copyf<<<(N_NODES * 3 + 255) / 256, 256, 0, stream>>>(pos0, pos, N_NODES * 3);

  // latent injection: h = MLP(cat[atom_types, z_exp])
  k_inj1<<<dim3(2, N_NODES / 64), 256, 0, stream>>>(at, z, injW1, injb1, t1);
  k_gemm128<1><<<N_NODES / 64, 256, 0, stream>>>(t1, injW2, injb2, t2, 256);
  k_gemm128<0><<<N_NODES / 64, 256, 0, stream>>>(t2, injW3, injb3, h, 128);

  for (int l = 0; l < NLAYER; ++l) {
    k_edge_fused<<<E_EDGES / 64, 256, 0, stream>>>(
        h, pos, rowsp, colsp, perm,
        eW1 + (size_t)l * 257 * HD, eb1 + l * HD,
        eW2 + (size_t)l * HD * HD, eb2 + l * HD,
        cW1 + (size_t)l * HD * HD, cb1 + l * HD, cW2 + (size_t)l * HD,
        m_s, rel_s, cw_s);
    k_node_gather<<<N_NODES / 2, 256, 0, stream>>>(m_s, cw_s, rel_s, offs, agg, pos);
    k_node_mlp<<<N_NODES / 64, 256, 0, stream>>>(h, agg, nW1 + (size_t)l * 2 * HD * HD, nb1 + l * HD,
                                                 nW2 + (size_t)l * HD * HD, nb2 + l * HD,
                                                 lng + l * HD, lnb + l * HD);
  }
  k_copyf<<<(N_NODES * 3 + 255) / 256, 256, 0, stream>>>(pos, (float*)d_out, N_NODES * 3);
}

// Round 6
// 1169.741 us; speedup vs baseline: 2.2001x; 2.2001x over previous
//
#include <hip/hip_runtime.h>
#include <cmath>

// Problem constants (match reference)
#define N_NODES 16384
#define E_EDGES 262144
#define HD 128
#define NLAYER 4

typedef __attribute__((ext_vector_type(8))) short bf16x8;
typedef __attribute__((ext_vector_type(4))) float f32x4;
#define MFMA16(a, b, c) __builtin_amdgcn_mfma_f32_16x16x32_bf16(a, b, c, 0, 0, 0)

__device__ __forceinline__ float silu_f(float x) { return x / (1.0f + expf(-x)); }

__device__ __forceinline__ unsigned short bf16_rn(float f) {
  union { float f; unsigned u; } v; v.f = f;
  unsigned r = (v.u + 0x7FFFu + ((v.u >> 16) & 1u)) >> 16;
  return (unsigned short)r;
}
__device__ __forceinline__ float bf16_tof(unsigned short h) {
  union { unsigned u; float f; } v; v.u = ((unsigned)h) << 16; return v.f;
}

// ---------------------------------------------------------------------------
// Weight prep: split fp32 weights into bf16 hi/lo and store FRAG-LINEAR:
// per layer: [half][chunk][slot=cf*64+l'][8], so edge-kernel B staging is a
// fully coalesced 16B/lane load -> contiguous LDS write, and each lane's MFMA
// B-fragment (B[k=(l>>4)*8+j][col=cf*16+(l&15)]) is slot l' of colfrag cf.
// e1f: 8 chunks (K=256), halfstride 32768; e2f/c1f: 4 chunks, halfstride 16384.
// ---------------------------------------------------------------------------
__global__ void k_prep_w(const float* __restrict__ eW1, const float* __restrict__ eW2,
                         const float* __restrict__ cW1,
                         unsigned short* __restrict__ e1f, unsigned short* __restrict__ e2f,
                         unsigned short* __restrict__ c1f) {
  int sid = blockIdx.x * 256 + threadIdx.x;  // 0..32767
  int layer = sid >> 13;
  int r = sid & 8191;
  const float* src; unsigned short* base; int c, s, halfstride;
  if (r < 4096) {
    c = r >> 9; s = r & 511;
    src = eW1 + (size_t)layer * 257 * 128;
    base = e1f + (size_t)layer * 65536; halfstride = 32768;
  } else if (r < 6144) {
    int rr = r - 4096; c = rr >> 9; s = rr & 511;
    src = eW2 + (size_t)layer * 128 * 128;
    base = e2f + (size_t)layer * 32768; halfstride = 16384;
  } else {
    int rr = r - 6144; c = rr >> 9; s = rr & 511;
    src = cW1 + (size_t)layer * 128 * 128;
    base = c1f + (size_t)layer * 32768; halfstride = 16384;
  }
  int cf = s >> 6, lp = s & 63;
  int n = cf * 16 + (lp & 15);
  int k0 = c * 32 + (lp >> 4) * 8;
  bf16x8 hv, lv;
#pragma unroll
  for (int j = 0; j < 8; ++j) {
    float w = src[(size_t)(k0 + j) * 128 + n];
    unsigned short h = bf16_rn(w);
    hv[j] = (short)h;
    lv[j] = (short)bf16_rn(w - bf16_tof(h));
  }
  size_t off = ((size_t)c * 512 + s) * 8;
  *(bf16x8*)(base + off) = hv;
  *(bf16x8*)(base + halfstride + off) = lv;
}

// h (f32 [N][128]) -> bf16 hi/lo arrays (per layer; hi/lo alias agg region)
__global__ void k_h2bf(const float* __restrict__ h, unsigned short* __restrict__ hhi,
                       unsigned short* __restrict__ hlo) {
  int i = (blockIdx.x * 256 + threadIdx.x) * 8;
  float4 a = *(const float4*)(h + i), b = *(const float4*)(h + i + 4);
  float v[8] = {a.x, a.y, a.z, a.w, b.x, b.y, b.z, b.w};
  bf16x8 hv, lv;
#pragma unroll
  for (int j = 0; j < 8; ++j) {
    unsigned short t = bf16_rn(v[j]);
    hv[j] = (short)t;
    lv[j] = (short)bf16_rn(v[j] - bf16_tof(t));
  }
  *(bf16x8*)(hhi + i) = hv;
  *(bf16x8*)(hlo + i) = lv;
}

// ---------------------------------------------------------------------------
// FUSED edge pipeline via split-bf16 MFMA (hi+lo, 3 products ~= fp32):
//   stage1: m1 = silu(cat(h[row],h[col],dsq) @ eW1 + eb1)   -> T (LDS, f32)
//   stage2: m2 = clip(silu(m1 @ eW2 + eb2))                 -> m_s + T
//   stage3: cw = silu(m2 @ cW1 + cb1) . cW2                 -> cw_s
// 64 CSR-sorted edges per block, 4 waves; wave w owns rows 16w..16w+15 (T is
// wave-private -> no barriers for T). Per K-chunk: B hi/lo staged to LDS from
// frag-linear global (coalesced), A-frags gathered from global h_hi/h_lo
// (CSR clustering -> L1-hot). dsq term applied exactly in f32 epilogue.
// ---------------------------------------------------------------------------
__global__ __launch_bounds__(256, 3) void k_edge_mfma(
    const unsigned short* __restrict__ hhi, const unsigned short* __restrict__ hlo,
    const float* __restrict__ pos,
    const int* __restrict__ rows, const int* __restrict__ cols, const int* __restrict__ perm,
    const unsigned short* __restrict__ e1f, const float* __restrict__ eW1,
    const float* __restrict__ eb1,
    const unsigned short* __restrict__ e2f, const float* __restrict__ eb2,
    const unsigned short* __restrict__ c1f, const float* __restrict__ cb1,
    const float* __restrict__ cW2,
    float* __restrict__ m_s, float* __restrict__ rel_s, float* __restrict__ cw_s) {
  __shared__ __align__(16) float T[64][132];      // 33.8 KB, f32 inter-stage acts
  __shared__ __align__(16) short Bl[2][4096];     // 16 KB: [hi/lo][cf*512 + lane*8]
  __shared__ int srow[64], scol[64];
  __shared__ float sdsq[64];

  const int tid = threadIdx.x;
  const int lane = tid & 63;
  const int w = tid >> 6;
  const int l15 = lane & 15, l4 = lane >> 4;
  const int j0 = blockIdx.x * 64;
  const f32x4 zero4 = {0.f, 0.f, 0.f, 0.f};

  if (tid < 64) {
    int e = perm[j0 + tid];
    int r = rows[e], c = cols[e];
    srow[tid] = r; scol[tid] = c;
    float rx = pos[r * 3 + 0] - pos[c * 3 + 0];
    float ry = pos[r * 3 + 1] - pos[c * 3 + 1];
    float rz = pos[r * 3 + 2] - pos[c * 3 + 2];
    rel_s[(size_t)(j0 + tid) * 3 + 0] = rx;
    rel_s[(size_t)(j0 + tid) * 3 + 1] = ry;
    rel_s[(size_t)(j0 + tid) * 3 + 2] = rz;
    float d = rx * rx + ry * ry + rz * rz;
    sdsq[tid] = fminf(fmaxf(d, 1e-6f), 1e6f);
  }

  f32x4 acc[8];

  // ---------------- stage 1: K=256 (8 chunks) ----------------
#pragma unroll
  for (int i = 0; i < 8; ++i) acc[i] = zero4;
  for (int c = 0; c < 8; ++c) {
    __syncthreads();  // prior chunk reads done (and preamble visible on c==0)
#pragma unroll
    for (int t = 0; t < 4; ++t) {
      int slot = tid + t * 256;               // 0..1023
      int half = slot >> 9, rem = slot & 511;
      const unsigned short* src = e1f + (size_t)half * 32768 + ((size_t)c * 512 + rem) * 8;
      *(bf16x8*)(&Bl[half][rem * 8]) = *(const bf16x8*)src;
    }
    __syncthreads();
    int node = (c < 4 ? srow : scol)[16 * w + l15];
    int koff = (c & 3) * 32 + l4 * 8;
    bf16x8 ah = *(const bf16x8*)(hhi + (size_t)node * 128 + koff);
    bf16x8 al = *(const bf16x8*)(hlo + (size_t)node * 128 + koff);
#pragma unroll
    for (int cf = 0; cf < 8; ++cf) {
      bf16x8 bh = *(const bf16x8*)(&Bl[0][cf * 512 + lane * 8]);
      bf16x8 bl = *(const bf16x8*)(&Bl[1][cf * 512 + lane * 8]);
      acc[cf] = MFMA16(ah, bh, acc[cf]);
      acc[cf] = MFMA16(al, bh, acc[cf]);
      acc[cf] = MFMA16(ah, bl, acc[cf]);
    }
  }
  // epilogue 1: + dsq*W[256] + bias, silu -> T (wave-private rows)
#pragma unroll
  for (int cf = 0; cf < 8; ++cf) {
    int col = cf * 16 + l15;
    float wl = eW1[256 * 128 + col];
    float bb = eb1[col];
#pragma unroll
    for (int r = 0; r < 4; ++r) {
      int trow = 16 * w + l4 * 4 + r;
      T[trow][col] = silu_f(acc[cf][r] + sdsq[trow] * wl + bb);
    }
  }

  // ---------------- stage 2: K=128 (4 chunks) ----------------
#pragma unroll
  for (int i = 0; i < 8; ++i) acc[i] = zero4;
  for (int c = 0; c < 4; ++c) {
    __syncthreads();
#pragma unroll
    for (int t = 0; t < 4; ++t) {
      int slot = tid + t * 256;
      int half = slot >> 9, rem = slot & 511;
      const unsigned short* src = e2f + (size_t)half * 16384 + ((size_t)c * 512 + rem) * 8;
      *(bf16x8*)(&Bl[half][rem * 8]) = *(const bf16x8*)src;
    }
    __syncthreads();
    int trow = 16 * w + l15;
    int k0 = c * 32 + l4 * 8;
    float tv[8];
    *(float4*)(tv) = *(const float4*)(&T[trow][k0]);
    *(float4*)(tv + 4) = *(const float4*)(&T[trow][k0 + 4]);
    bf16x8 ah, al;
#pragma unroll
    for (int j = 0; j < 8; ++j) {
      unsigned short t = bf16_rn(tv[j]);
      ah[j] = (short)t;
      al[j] = (short)bf16_rn(tv[j] - bf16_tof(t));
    }
#pragma unroll
    for (int cf = 0; cf < 8; ++cf) {
      bf16x8 bh = *(const bf16x8*)(&Bl[0][cf * 512 + lane * 8]);
      bf16x8 bl = *(const bf16x8*)(&Bl[1][cf * 512 + lane * 8]);
      acc[cf] = MFMA16(ah, bh, acc[cf]);
      acc[cf] = MFMA16(al, bh, acc[cf]);
      acc[cf] = MFMA16(ah, bl, acc[cf]);
    }
  }
  // epilogue 2: bias + silu + clip -> m_s (global) and T (in-place, own rows)
#pragma unroll
  for (int cf = 0; cf < 8; ++cf) {
    int col = cf * 16 + l15;
    float bb = eb2[col];
#pragma unroll
    for (int r = 0; r < 4; ++r) {
      int trow = 16 * w + l4 * 4 + r;
      float v = silu_f(acc[cf][r] + bb);
      v = fminf(fmaxf(v, -10.0f), 10.0f);
      m_s[(size_t)(j0 + trow) * 128 + col] = v;
      T[trow][col] = v;
    }
  }

  // ---------------- stage 3: K=128 (4 chunks) ----------------
#pragma unroll
  for (int i = 0; i < 8; ++i) acc[i] = zero4;
  for (int c = 0; c < 4; ++c) {
    __syncthreads();
#pragma unroll
    for (int t = 0; t < 4; ++t) {
      int slot = tid + t * 256;
      int half = slot >> 9, rem = slot & 511;
      const unsigned short* src = c1f + (size_t)half * 16384 + ((size_t)c * 512 + rem) * 8;
      *(bf16x8*)(&Bl[half][rem * 8]) = *(const bf16x8*)src;
    }
    __syncthreads();
    int trow = 16 * w + l15;
    int k0 = c * 32 + l4 * 8;
    float tv[8];
    *(float4*)(tv) = *(const float4*)(&T[trow][k0]);
    *(float4*)(tv + 4) = *(const float4*)(&T[trow][k0 + 4]);
    bf16x8 ah, al;
#pragma unroll
    for (int j = 0; j < 8; ++j) {
      unsigned short t = bf16_rn(tv[j]);
      ah[j] = (short)t;
      al[j] = (short)bf16_rn(tv[j] - bf16_tof(t));
    }
#pragma unroll
    for (int cf = 0; cf < 8; ++cf) {
      bf16x8 bh = *(const bf16x8*)(&Bl[0][cf * 512 + lane * 8]);
      bf16x8 bl = *(const bf16x8*)(&Bl[1][cf * 512 + lane * 8]);
      acc[cf] = MFMA16(ah, bh, acc[cf]);
      acc[cf] = MFMA16(al, bh, acc[cf]);
      acc[cf] = MFMA16(ah, bl, acc[cf]);
    }
  }
  // epilogue 3: silu + dot with cW2, reduce over 16 col-residues -> cw_s
  {
    float p[4] = {0.f, 0.f, 0.f, 0.f};
#pragma unroll
    for (int cf = 0; cf < 8; ++cf) {
      int col = cf * 16 + l15;
      float bb = cb1[col];
      float w2 = cW2[col];
#pragma unroll
      for (int r = 0; r < 4; ++r) p[r] += silu_f(acc[cf][r] + bb) * w2;
    }
#pragma unroll
    for (int d = 1; d < 16; d <<= 1) {
#pragma unroll
      for (int r = 0; r < 4; ++r) p[r] += __shfl_xor(p[r], d);
    }
    if (l15 == 0) {
#pragma unroll
      for (int r = 0; r < 4; ++r) cw_s[j0 + 16 * w + l4 * 4 + r] = p[r];
    }
  }
}

// ---------------------------------------------------------------------------
// Generic fp32 GEMM (injector layers 2/3 only)
// ---------------------------------------------------------------------------
template <int ACT>
__global__ __launch_bounds__(256, 2) void k_gemm128(const float* Ag, const float* __restrict__ W,
                                                    const float* __restrict__ bias, float* C, int K) {
  __shared__ float As[64][33];
  __shared__ float Ws[32][128];
  const int tid = threadIdx.x;
  const int tc = tid & 15, tr = tid >> 4;
  const int tr4 = tr * 4, tc4 = tc * 4;
  const int m0 = blockIdx.x * 64;

  float acc[4][8];
#pragma unroll
  for (int i = 0; i < 4; ++i)
#pragma unroll
    for (int j = 0; j < 8; ++j) acc[i][j] = 0.0f;

  for (int kk = 0; kk < K; kk += 32) {
    int idx = tid;
#pragma unroll
    for (int it = 0; it < 2; ++it, idx += 256) {
      int r = idx >> 3, c4 = (idx & 7) << 2;
      float4 v = *(const float4*)(Ag + (size_t)(m0 + r) * K + kk + c4);
      As[r][c4] = v.x; As[r][c4 + 1] = v.y; As[r][c4 + 2] = v.z; As[r][c4 + 3] = v.w;
    }
    idx = tid;
#pragma unroll
    for (int it = 0; it < 4; ++it, idx += 256) {
      int r = idx >> 5, c4 = (idx & 31) << 2;
      *(float4*)(&Ws[r][c4]) = *(const float4*)(W + (size_t)(kk + r) * 128 + c4);
    }
    __syncthreads();
#pragma unroll
    for (int k = 0; k < 32; ++k) {
      float av[4];
#pragma unroll
      for (int i = 0; i < 4; ++i) av[i] = As[tr4 + i][k];
      float4 b0 = *(const float4*)(&Ws[k][tc4]);
      float4 b1 = *(const float4*)(&Ws[k][64 + tc4]);
      float bv[8] = {b0.x, b0.y, b0.z, b0.w, b1.x, b1.y, b1.z, b1.w};
#pragma unroll
      for (int i = 0; i < 4; ++i)
#pragma unroll
        for (int j = 0; j < 8; ++j) acc[i][j] = fmaf(av[i], bv[j], acc[i][j]);
    }
    __syncthreads();
  }

  float bv0[8];
#pragma unroll
  for (int j = 0; j < 4; ++j) { bv0[j] = bias[tc4 + j]; bv0[4 + j] = bias[64 + tc4 + j]; }
#pragma unroll
  for (int i = 0; i < 4; ++i) {
    size_t row = m0 + tr4 + i;
    float o[8];
#pragma unroll
    for (int j = 0; j < 8; ++j) {
      float v = acc[i][j] + bv0[j];
      if (ACT >= 1) v = silu_f(v);
      o[j] = v;
    }
    *(float4*)(C + row * 128 + tc4) = make_float4(o[0], o[1], o[2], o[3]);
    *(float4*)(C + row * 128 + 64 + tc4) = make_float4(o[4], o[5], o[6], o[7]);
  }
}

// ---------------------------------------------------------------------------
// CSR build
// ---------------------------------------------------------------------------
__global__ void k_count(const int* __restrict__ rows, int* __restrict__ cnt) {
  int e = blockIdx.x * 256 + threadIdx.x;
  if (e < E_EDGES) atomicAdd(&cnt[rows[e]], 1);
}

__global__ void k_scan(const int* __restrict__ cnt, int* __restrict__ offs) {
  __shared__ int part[256];
  const int tid = threadIdx.x;
  const int base = tid * 64;
  int s = 0;
  for (int i = 0; i < 64; ++i) s += cnt[base + i];
  part[tid] = s;
  __syncthreads();
  for (int d = 1; d < 256; d <<= 1) {
    int v = (tid >= d) ? part[tid - d] : 0;
    __syncthreads();
    part[tid] += v;
    __syncthreads();
  }
  int run = part[tid] - s;
  for (int i = 0; i < 64; ++i) { offs[base + i] = run; run += cnt[base + i]; }
  if (tid == 255) offs[N_NODES] = run;
}

__global__ void k_fill(const int* __restrict__ rows, const int* __restrict__ offs,
                       int* __restrict__ fill, int* __restrict__ perm) {
  int e = blockIdx.x * 256 + threadIdx.x;
  if (e < E_EDGES) {
    int r = rows[e];
    int p = atomicAdd(&fill[r], 1);
    perm[offs[r] + p] = e;
  }
}

// ---------------------------------------------------------------------------
// Per-node gather (CSR-contiguous): 4 accumulators for load ILP
// ---------------------------------------------------------------------------
__global__ void k_node_gather(const float* __restrict__ m_s, const float* __restrict__ cw_s,
                              const float* __restrict__ rel_s, const int* __restrict__ offs,
                              float* __restrict__ agg, float* __restrict__ pos) {
  const int node = blockIdx.x * 2 + (threadIdx.x >> 7);
  const int c = threadIdx.x & 127;
  const int o0 = offs[node], o1 = offs[node + 1];
  float s0 = 0.f, s1 = 0.f, s2 = 0.f, s3 = 0.f;
  int j = o0;
  for (; j + 4 <= o1; j += 4) {
    s0 += m_s[(size_t)j * 128 + c];
    s1 += m_s[(size_t)(j + 1) * 128 + c];
    s2 += m_s[(size_t)(j + 2) * 128 + c];
    s3 += m_s[(size_t)(j + 3) * 128 + c];
  }
  for (; j < o1; ++j) s0 += m_s[(size_t)j * 128 + c];
  agg[(size_t)node * 128 + c] = (s0 + s1) + (s2 + s3);
  if (c < 3) {
    float cu = 0.0f;
    for (int jj = o0; jj < o1; ++jj) cu += cw_s[jj] * rel_s[(size_t)jj * 3 + c];
    float deg = (float)(o1 - o0);
    pos[node * 3 + c] += cu / (deg + 1e-6f);
  }
}

// ---------------------------------------------------------------------------
// Node MLP + residual + LayerNorm (fused, in-place on h)
// ---------------------------------------------------------------------------
__global__ __launch_bounds__(256, 2) void k_node_mlp(float* __restrict__ h, const float* __restrict__ agg,
                                                     const float* __restrict__ W1, const float* __restrict__ b1,
                                                     const float* __restrict__ W2, const float* __restrict__ b2,
                                                     const float* __restrict__ lng, const float* __restrict__ lnb) {
  __shared__ float As[64][33];
  __shared__ float Ws[32][128];
  __shared__ float T[64][132];
  const int tid = threadIdx.x;
  const int tc = tid & 15, tr = tid >> 4;
  const int tr4 = tr * 4, tc4 = tc * 4;
  const int m0 = blockIdx.x * 64;

  float acc[4][8];
#pragma unroll
  for (int i = 0; i < 4; ++i)
#pragma unroll
    for (int j = 0; j < 8; ++j) acc[i][j] = 0.0f;

  for (int kk = 0; kk < 256; kk += 32) {
    const float* src = (kk < 128) ? h : agg;
    const int kb = kk & 127;
    int idx = tid;
#pragma unroll
    for (int it = 0; it < 2; ++it, idx += 256) {
      int r = idx >> 3, c4 = (idx & 7) << 2;
      float4 v = *(const float4*)(src + (size_t)(m0 + r) * 128 + kb + c4);
      As[r][c4] = v.x; As[r][c4 + 1] = v.y; As[r][c4 + 2] = v.z; As[r][c4 + 3] = v.w;
    }
    idx = tid;
#pragma unroll
    for (int it = 0; it < 4; ++it, idx += 256) {
      int r = idx >> 5, c4 = (idx & 31) << 2;
      *(float4*)(&Ws[r][c4]) = *(const float4*)(W1 + (size_t)(kk + r) * 128 + c4);
    }
    __syncthreads();
#pragma unroll
    for (int k = 0; k < 32; ++k) {
      float av[4];
#pragma unroll
      for (int i = 0; i < 4; ++i) av[i] = As[tr4 + i][k];
      float4 b0 = *(const float4*)(&Ws[k][tc4]);
      float4 b1v = *(const float4*)(&Ws[k][64 + tc4]);
      float bv[8] = {b0.x, b0.y, b0.z, b0.w, b1v.x, b1v.y, b1v.z, b1v.w};
#pragma unroll
      for (int i = 0; i < 4; ++i)
#pragma unroll
        for (int j = 0; j < 8; ++j) acc[i][j] = fmaf(av[i], bv[j], acc[i][j]);
    }
    __syncthreads();
  }
#pragma unroll
  for (int i = 0; i < 4; ++i) {
#pragma unroll
    for (int j = 0; j < 4; ++j) {
      T[tr4 + i][tc4 + j] = silu_f(acc[i][j] + b1[tc4 + j]);
      T[tr4 + i][64 + tc4 + j] = silu_f(acc[i][4 + j] + b1[64 + tc4 + j]);
    }
  }
  __syncthreads();

  float acc2[4][8];
#pragma unroll
  for (int i = 0; i < 4; ++i)
#pragma unroll
    for (int j = 0; j < 8; ++j) acc2[i][j] = 0.0f;
  for (int kk = 0; kk < 128; kk += 32) {
    int idx = tid;
#pragma unroll
    for (int it = 0; it < 4; ++it, idx += 256) {
      int r = idx >> 5, c4 = (idx & 31) << 2;
      *(float4*)(&Ws[r][c4]) = *(const float4*)(W2 + (size_t)(kk + r) * 128 + c4);
    }
    __syncthreads();
#pragma unroll
    for (int k = 0; k < 32; ++k) {
      float av[4];
#pragma unroll
      for (int i = 0; i < 4; ++i) av[i] = T[tr4 + i][kk + k];
      float4 b0 = *(const float4*)(&Ws[k][tc4]);
      float4 b1v = *(const float4*)(&Ws[k][64 + tc4]);
      float bv[8] = {b0.x, b0.y, b0.z, b0.w, b1v.x, b1v.y, b1v.z, b1v.w};
#pragma unroll
      for (int i = 0; i < 4; ++i)
#pragma unroll
        for (int j = 0; j < 8; ++j) acc2[i][j] = fmaf(av[i], bv[j], acc2[i][j]);
    }
    __syncthreads();
  }

  float x[4][8], s1[4], s2[4];
#pragma unroll
  for (int i = 0; i < 4; ++i) {
    size_t row = m0 + tr4 + i;
    float4 h0 = *(const float4*)(h + row * 128 + tc4);
    float4 h1 = *(const float4*)(h + row * 128 + 64 + tc4);
    float hv[8] = {h0.x, h0.y, h0.z, h0.w, h1.x, h1.y, h1.z, h1.w};
    s1[i] = 0.f; s2[i] = 0.f;
#pragma unroll
    for (int j = 0; j < 8; ++j) {
      int cidx = (j < 4) ? (tc4 + j) : (64 + tc4 + (j - 4));
      float v = hv[j] + acc2[i][j] + b2[cidx];
      x[i][j] = v;
      s1[i] += v;
      s2[i] += v * v;
    }
  }
#pragma unroll
  for (int d = 1; d < 16; d <<= 1) {
#pragma unroll
    for (int i = 0; i < 4; ++i) {
      s1[i] += __shfl_xor(s1[i], d);
      s2[i] += __shfl_xor(s2[i], d);
    }
  }
  float gv[8], bvv[8];
#pragma unroll
  for (int j = 0; j < 4; ++j) {
    gv[j] = lng[tc4 + j]; gv[4 + j] = lng[64 + tc4 + j];
    bvv[j] = lnb[tc4 + j]; bvv[4 + j] = lnb[64 + tc4 + j];
  }
#pragma unroll
  for (int i = 0; i < 4; ++i) {
    float mu = s1[i] * (1.0f / 128.0f);
    float var = s2[i] * (1.0f / 128.0f) - mu * mu;
    float rs = rsqrtf(var + 1e-5f);
    size_t row = m0 + tr4 + i;
    float o[8];
#pragma unroll
    for (int j = 0; j < 8; ++j) o[j] = (x[i][j] - mu) * rs * gv[j] + bvv[j];
    *(float4*)(h + row * 128 + tc4) = make_float4(o[0], o[1], o[2], o[3]);
    *(float4*)(h + row * 128 + 64 + tc4) = make_float4(o[4], o[5], o[6], o[7]);
  }
}

// ---------------------------------------------------------------------------
// Injector layer 1
// ---------------------------------------------------------------------------
__global__ __launch_bounds__(256) void k_inj1(const float* __restrict__ at, const float* __restrict__ z,
                                              const float* __restrict__ W1, const float* __restrict__ b1,
                                              float* __restrict__ out) {
  __shared__ float As[64][84];
  __shared__ float Ws[80][128];
  const int tid = threadIdx.x;
  const int tc = tid & 15, tr = tid >> 4;
  const int tr4 = tr * 4, tc4 = tc * 4;
  const int m0 = blockIdx.y * 64;
  const int cb = blockIdx.x * 128;

  int idx = tid;
#pragma unroll
  for (int it = 0; it < 5; ++it, idx += 256) {
    int r = idx / 20, c4 = idx % 20;
    int n = m0 + r;
    float4 v;
    if (c4 < 4) v = *(const float4*)(at + (size_t)n * 16 + c4 * 4);
    else v = *(const float4*)(z + (size_t)(n >> 6) * 64 + (c4 - 4) * 4);
    *(float4*)(&As[r][c4 * 4]) = v;
  }
  idx = tid;
#pragma unroll
  for (int it = 0; it < 10; ++it, idx += 256) {
    int r = idx >> 5, c4 = (idx & 31) << 2;
    *(float4*)(&Ws[r][c4]) = *(const float4*)(W1 + (size_t)r * 256 + cb + c4);
  }
  __syncthreads();

  float acc[4][8];
#pragma unroll
  for (int i = 0; i < 4; ++i)
#pragma unroll
    for (int j = 0; j < 8; ++j) acc[i][j] = 0.0f;
#pragma unroll 4
  for (int k = 0; k < 80; ++k) {
    float av[4];
#pragma unroll
    for (int i = 0; i < 4; ++i) av[i] = As[tr4 + i][k];
    float4 b0 = *(const float4*)(&Ws[k][tc4]);
    float4 b1v = *(const float4*)(&Ws[k][64 + tc4]);
    float bv[8] = {b0.x, b0.y, b0.z, b0.w, b1v.x, b1v.y, b1v.z, b1v.w};
#pragma unroll
    for (int i = 0; i < 4; ++i)
#pragma unroll
      for (int j = 0; j < 8; ++j) acc[i][j] = fmaf(av[i], bv[j], acc[i][j]);
  }

  float bb[8];
#pragma unroll
  for (int j = 0; j < 4; ++j) { bb[j] = b1[cb + tc4 + j]; bb[4 + j] = b1[cb + 64 + tc4 + j]; }
#pragma unroll
  for (int i = 0; i < 4; ++i) {
    size_t row = m0 + tr4 + i;
    float o[8];
#pragma unroll
    for (int j = 0; j < 8; ++j) o[j] = silu_f(acc[i][j] + bb[j]);
    *(float4*)(out + row * 256 + cb + tc4) = make_float4(o[0], o[1], o[2], o[3]);
    *(float4*)(out + row * 256 + cb + 64 + tc4) = make_float4(o[4], o[5], o[6], o[7]);
  }
}

__global__ void k_copyf(const float* __restrict__ in, float* __restrict__ out, int n) {
  int i = blockIdx.x * 256 + threadIdx.x;
  if (i < n) out[i] = in[i];
}

// ---------------------------------------------------------------------------
extern "C" void kernel_launch(void* const* d_in, const int* in_sizes, int n_in,
                              void* d_out, int out_size, void* d_ws, size_t ws_size,
                              hipStream_t stream) {
  const float* z = (const float*)d_in[0];
  const float* at = (const float*)d_in[1];
  const float* pos0 = (const float*)d_in[2];
  const int* ei = (const int*)d_in[3];
  const float* injW1 = (const float*)d_in[4];
  const float* injb1 = (const float*)d_in[5];
  const float* injW2 = (const float*)d_in[6];
  const float* injb2 = (const float*)d_in[7];
  const float* injW3 = (const float*)d_in[8];
  const float* injb3 = (const float*)d_in[9];
  const float* eW1 = (const float*)d_in[10];
  const float* eb1 = (const float*)d_in[11];
  const float* eW2 = (const float*)d_in[12];
  const float* eb2 = (const float*)d_in[13];
  const float* cW1 = (const float*)d_in[14];
  const float* cb1 = (const float*)d_in[15];
  const float* cW2 = (const float*)d_in[16];
  const float* nW1 = (const float*)d_in[17];
  const float* nb1 = (const float*)d_in[18];
  const float* nW2 = (const float*)d_in[19];
  const float* nb2 = (const float*)d_in[20];
  const float* lng = (const float*)d_in[21];
  const float* lnb = (const float*)d_in[22];

  float* w = (float*)d_ws;
  float* h = w;    w += (size_t)N_NODES * HD;
  float* pos = w;  w += (size_t)N_NODES * 3;
  float* m_s = w;  w += (size_t)E_EDGES * HD;
  float* rel_s = w; w += (size_t)E_EDGES * 3;
  float* cw_s = w; w += (size_t)E_EDGES;
  float* agg = w;  w += (size_t)N_NODES * HD;
  float* t1 = m_s;   // alias (injection phase only), [N,256]
  float* t2 = agg;   // alias (injection phase only), [N,128]
  // h bf16 hi/lo alias the agg region (lifetimes disjoint: hhi/hlo live
  // h2bf->edge_mfma; agg written by node_gather AFTER edge_mfma completes)
  unsigned short* hhi = (unsigned short*)agg;
  unsigned short* hlo = hhi + (size_t)N_NODES * HD;
  int* ib = (int*)w;
  int* cnt = ib;  ib += N_NODES;
  int* offs = ib; ib += N_NODES + 1;
  int* fill = ib; ib += N_NODES;
  int* perm = ib; ib += E_EDGES;
  // frag-linear split weights (new, +1 MB)
  unsigned short* e1f = (unsigned short*)ib;                 // 4 * 65536
  unsigned short* e2f = e1f + (size_t)4 * 65536;             // 4 * 32768
  unsigned short* c1f = e2f + (size_t)4 * 32768;             // 4 * 32768

  const int* rowsp = ei;
  const int* colsp = ei + E_EDGES;

  // CSR build
  hipMemsetAsync(cnt, 0, N_NODES * sizeof(int), stream);
  hipMemsetAsync(fill, 0, N_NODES * sizeof(int), stream);
  k_count<<<E_EDGES / 256, 256, 0, stream>>>(rowsp, cnt);
  k_scan<<<1, 256, 0, stream>>>(cnt, offs);
  k_fill<<<E_EDGES / 256, 256, 0, stream>>>(rowsp, offs, fill, perm);
  k_copyf<<<(N_NODES * 3 + 255) / 256, 256, 0, stream>>>(pos0, pos, N_NODES * 3);

  // weight prep (frag-linear bf16 hi/lo)
  k_prep_w<<<128, 256, 0, stream>>>(eW1, eW2, cW1, e1f, e2f, c1f);

  // latent injection
  k_inj1<<<dim3(2, N_NODES / 64), 256, 0, stream>>>(at, z, injW1, injb1, t1);
  k_gemm128<1><<<N_NODES / 64, 256, 0, stream>>>(t1, injW2, injb2, t2, 256);
  k_gemm128<0><<<N_NODES / 64, 256, 0, stream>>>(t2, injW3, injb3, h, 128);

  for (int l = 0; l < NLAYER; ++l) {
    k_h2bf<<<(N_NODES * HD / 8) / 256, 256, 0, stream>>>(h, hhi, hlo);
    k_edge_mfma<<<E_EDGES / 64, 256, 0, stream>>>(
        hhi, hlo, pos, rowsp, colsp, perm,
        e1f + (size_t)l * 65536, eW1 + (size_t)l * 257 * HD, eb1 + l * HD,
        e2f + (size_t)l * 32768, eb2 + l * HD,
        c1f + (size_t)l * 32768, cb1 + l * HD,
        cW2 + (size_t)l * HD,
        m_s, rel_s, cw_s);
    k_node_gather<<<N_NODES / 2, 256, 0, stream>>>(m_s, cw_s, rel_s, offs, agg, pos);
    k_node_mlp<<<N_NODES / 64, 256, 0, stream>>>(h, agg, nW1 + (size_t)l * 2 * HD * HD, nb1 + l * HD,
                                                 nW2 + (size_t)l * HD * HD, nb2 + l * HD,
                                                 lng + l * HD, lnb + l * HD);
  }
  k_copyf<<<(N_NODES * 3 + 255) / 256, 256, 0, stream>>>(pos, (float*)d_out, N_NODES * 3);
}

// Round 8
// 1087.804 us; speedup vs baseline: 2.3658x; 1.0753x over previous
//
#include <hip/hip_runtime.h>
#include <cmath>

// Problem constants (match reference)
#define N_NODES 16384
#define E_EDGES 262144
#define HD 128
#define NLAYER 4

typedef __attribute__((ext_vector_type(8))) short bf16x8;
typedef __attribute__((ext_vector_type(4))) float f32x4;
#define MFMA16(a, b, c) __builtin_amdgcn_mfma_f32_16x16x32_bf16(a, b, c, 0, 0, 0)

// fast silu: v_exp + v_rcp (~4 ops) instead of libm expf (~20). err ~1e-7 rel.
__device__ __forceinline__ float silu_f(float x) {
  return __fdividef(x, 1.0f + __expf(-x));
}

__device__ __forceinline__ unsigned short bf16_rn(float f) {
  union { float f; unsigned u; } v; v.f = f;
  unsigned r = (v.u + 0x7FFFu + ((v.u >> 16) & 1u)) >> 16;
  return (unsigned short)r;
}
__device__ __forceinline__ float bf16_tof(unsigned short h) {
  union { unsigned u; float f; } v; v.u = ((unsigned)h) << 16; return v.f;
}

// ---------------------------------------------------------------------------
// Weight prep: split fp32 weights into bf16 hi/lo (RN, runs once) FRAG-LINEAR:
// per layer: [half][chunk][slot=cf*64+l'][8]; B-frag of lane l', colfrag cf is
// B[k=(l'>>4)*8+j][col=cf*16+(l'&15)].
// ---------------------------------------------------------------------------
__global__ void k_prep_w(const float* __restrict__ eW1, const float* __restrict__ eW2,
                         const float* __restrict__ cW1,
                         unsigned short* __restrict__ e1f, unsigned short* __restrict__ e2f,
                         unsigned short* __restrict__ c1f) {
  int sid = blockIdx.x * 256 + threadIdx.x;  // 0..32767
  int layer = sid >> 13;
  int r = sid & 8191;
  const float* src; unsigned short* base; int c, s, halfstride;
  if (r < 4096) {
    c = r >> 9; s = r & 511;
    src = eW1 + (size_t)layer * 257 * 128;
    base = e1f + (size_t)layer * 65536; halfstride = 32768;
  } else if (r < 6144) {
    int rr = r - 4096; c = rr >> 9; s = rr & 511;
    src = eW2 + (size_t)layer * 128 * 128;
    base = e2f + (size_t)layer * 32768; halfstride = 16384;
  } else {
    int rr = r - 6144; c = rr >> 9; s = rr & 511;
    src = cW1 + (size_t)layer * 128 * 128;
    base = c1f + (size_t)layer * 32768; halfstride = 16384;
  }
  int cf = s >> 6, lp = s & 63;
  int n = cf * 16 + (lp & 15);
  int k0 = c * 32 + (lp >> 4) * 8;
  bf16x8 hv, lv;
#pragma unroll
  for (int j = 0; j < 8; ++j) {
    float w = src[(size_t)(k0 + j) * 128 + n];
    unsigned short h = bf16_rn(w);
    hv[j] = (short)h;
    lv[j] = (short)bf16_rn(w - bf16_tof(h));
  }
  size_t off = ((size_t)c * 512 + s) * 8;
  *(bf16x8*)(base + off) = hv;
  *(bf16x8*)(base + halfstride + off) = lv;
}

// h (f32 [N][128]) -> bf16 hi(trunc)/lo arrays
__global__ void k_h2bf(const float* __restrict__ h, unsigned short* __restrict__ hhi,
                       unsigned short* __restrict__ hlo) {
  int i = (blockIdx.x * 256 + threadIdx.x) * 8;
  float4 a = *(const float4*)(h + i), b = *(const float4*)(h + i + 4);
  float v[8] = {a.x, a.y, a.z, a.w, b.x, b.y, b.z, b.w};
  bf16x8 hv, lv;
#pragma unroll
  for (int j = 0; j < 8; ++j) {
    unsigned u = __float_as_uint(v[j]);
    hv[j] = (short)(u >> 16);                                  // truncated hi
    float hi_f = __uint_as_float(u & 0xFFFF0000u);
    lv[j] = (short)bf16_rn(v[j] - hi_f);                       // exact remainder, RN
  }
  *(bf16x8*)(hhi + i) = hv;
  *(bf16x8*)(hlo + i) = lv;
}

// ---------------------------------------------------------------------------
// FUSED edge pipeline, split-bf16 MFMA + IN-KERNEL AGGREGATION:
//   stage1: m1 = silu(cat(h[row],h[col],dsq) @ eW1 + eb1)   -> T (LDS, f32)
//   stage2: m2 = clip(silu(m1 @ eW2 + eb2))  -> T, segment-sum -> agg (atomic)
//   stage3: cw = silu(m2 @ cW1 + cb1).cW2    -> cw*rel segment-sum -> coordacc
// m is NEVER materialized to HBM (saves 135MB wr + 134MB rd per layer).
// Edges CSR-sorted; wave w owns rows 16w..16w+15 (T wave-private). Segments
// within a wave's 16-edge window found by scanning srow (non-decreasing);
// cross-wave/block portions combine via atomics on zeroed agg/coordacc.
// ---------------------------------------------------------------------------
__global__ __launch_bounds__(256, 3) void k_edge_mfma(
    const unsigned short* __restrict__ hhi, const unsigned short* __restrict__ hlo,
    const float* __restrict__ pos,
    const int* __restrict__ rows, const int* __restrict__ cols, const int* __restrict__ perm,
    const unsigned short* __restrict__ e1f, const float* __restrict__ eW1,
    const float* __restrict__ eb1,
    const unsigned short* __restrict__ e2f, const float* __restrict__ eb2,
    const unsigned short* __restrict__ c1f, const float* __restrict__ cb1,
    const float* __restrict__ cW2,
    float* __restrict__ agg, float* __restrict__ coordacc) {
  __shared__ __align__(16) float T[64][132];      // 33.8 KB inter-stage acts
  __shared__ __align__(16) short Bl[2][4096];     // 16 KB B-frags hi/lo
  __shared__ int srow[64], scol[64];
  __shared__ float sdsq[64];
  __shared__ float srel[64][4];                   // rel vectors (LDS only)

  const int tid = threadIdx.x;
  const int lane = tid & 63;
  const int w = tid >> 6;
  const int l15 = lane & 15, l4 = lane >> 4;
  const int j0 = blockIdx.x * 64;
  const f32x4 zero4 = {0.f, 0.f, 0.f, 0.f};

  if (tid < 64) {
    int e = perm[j0 + tid];
    int r = rows[e], c = cols[e];
    srow[tid] = r; scol[tid] = c;
    float rx = pos[r * 3 + 0] - pos[c * 3 + 0];
    float ry = pos[r * 3 + 1] - pos[c * 3 + 1];
    float rz = pos[r * 3 + 2] - pos[c * 3 + 2];
    srel[tid][0] = rx; srel[tid][1] = ry; srel[tid][2] = rz;
    float d = rx * rx + ry * ry + rz * rz;
    sdsq[tid] = fminf(fmaxf(d, 1e-6f), 1e6f);
  }

  f32x4 acc[8];

  // ---------------- stage 1: K=256 (8 chunks) ----------------
#pragma unroll
  for (int i = 0; i < 8; ++i) acc[i] = zero4;
  for (int c = 0; c < 8; ++c) {
    __syncthreads();
#pragma unroll
    for (int t = 0; t < 4; ++t) {
      int slot = tid + t * 256;
      int half = slot >> 9, rem = slot & 511;
      const unsigned short* src = e1f + (size_t)half * 32768 + ((size_t)c * 512 + rem) * 8;
      *(bf16x8*)(&Bl[half][rem * 8]) = *(const bf16x8*)src;
    }
    __syncthreads();
    int node = (c < 4 ? srow : scol)[16 * w + l15];
    int koff = (c & 3) * 32 + l4 * 8;
    bf16x8 ah = *(const bf16x8*)(hhi + (size_t)node * 128 + koff);
    bf16x8 al = *(const bf16x8*)(hlo + (size_t)node * 128 + koff);
#pragma unroll
    for (int cf = 0; cf < 8; ++cf) {
      bf16x8 bh = *(const bf16x8*)(&Bl[0][cf * 512 + lane * 8]);
      bf16x8 bl = *(const bf16x8*)(&Bl[1][cf * 512 + lane * 8]);
      acc[cf] = MFMA16(ah, bh, acc[cf]);
      acc[cf] = MFMA16(al, bh, acc[cf]);
      acc[cf] = MFMA16(ah, bl, acc[cf]);
    }
  }
  // epilogue 1: + dsq*W[256] + bias, silu -> T
#pragma unroll
  for (int cf = 0; cf < 8; ++cf) {
    int col = cf * 16 + l15;
    float wl = eW1[256 * 128 + col];
    float bb = eb1[col];
#pragma unroll
    for (int r = 0; r < 4; ++r) {
      int trow = 16 * w + l4 * 4 + r;
      T[trow][col] = silu_f(acc[cf][r] + sdsq[trow] * wl + bb);
    }
  }

  // ---------------- stage 2: K=128 (4 chunks) ----------------
#pragma unroll
  for (int i = 0; i < 8; ++i) acc[i] = zero4;
  for (int c = 0; c < 4; ++c) {
    __syncthreads();
#pragma unroll
    for (int t = 0; t < 4; ++t) {
      int slot = tid + t * 256;
      int half = slot >> 9, rem = slot & 511;
      const unsigned short* src = e2f + (size_t)half * 16384 + ((size_t)c * 512 + rem) * 8;
      *(bf16x8*)(&Bl[half][rem * 8]) = *(const bf16x8*)src;
    }
    __syncthreads();
    int trow = 16 * w + l15;
    int k0 = c * 32 + l4 * 8;
    float tv[8];
    *(float4*)(tv) = *(const float4*)(&T[trow][k0]);
    *(float4*)(tv + 4) = *(const float4*)(&T[trow][k0 + 4]);
    bf16x8 ah, al;
#pragma unroll
    for (int j = 0; j < 8; ++j) {
      unsigned u = __float_as_uint(tv[j]);
      ah[j] = (short)(u >> 16);
      float hi_f = __uint_as_float(u & 0xFFFF0000u);
      al[j] = (short)bf16_rn(tv[j] - hi_f);
    }
#pragma unroll
    for (int cf = 0; cf < 8; ++cf) {
      bf16x8 bh = *(const bf16x8*)(&Bl[0][cf * 512 + lane * 8]);
      bf16x8 bl = *(const bf16x8*)(&Bl[1][cf * 512 + lane * 8]);
      acc[cf] = MFMA16(ah, bh, acc[cf]);
      acc[cf] = MFMA16(al, bh, acc[cf]);
      acc[cf] = MFMA16(ah, bl, acc[cf]);
    }
  }
  // epilogue 2: bias+silu+clip -> T (stage 3 input) + segment-sum -> agg
#pragma unroll
  for (int cf = 0; cf < 8; ++cf) {
    int col = cf * 16 + l15;
    float bb = eb2[col];
#pragma unroll
    for (int r = 0; r < 4; ++r) {
      int trow = 16 * w + l4 * 4 + r;
      float v = silu_f(acc[cf][r] + bb);
      v = fminf(fmaxf(v, -10.0f), 10.0f);
      acc[cf][r] = v;            // keep for segment sum
      T[trow][col] = v;
    }
  }
  {
    int seg = 0;
    while (seg < 16) {           // wave-uniform scan over CSR runs
      int node = srow[16 * w + seg];
      int se = seg + 1;
      while (se < 16 && srow[16 * w + se] == node) ++se;
#pragma unroll
      for (int cf = 0; cf < 8; ++cf) {
        float s = 0.f;
#pragma unroll
        for (int r = 0; r < 4; ++r) {
          int row = l4 * 4 + r;
          s += (row >= seg && row < se) ? acc[cf][r] : 0.f;
        }
        s += __shfl_xor(s, 16);
        s += __shfl_xor(s, 32);
        if (l4 == 0) atomicAdd(&agg[(size_t)node * 128 + cf * 16 + l15], s);
      }
      seg = se;
    }
  }

  // ---------------- stage 3: K=128 (4 chunks) ----------------
#pragma unroll
  for (int i = 0; i < 8; ++i) acc[i] = zero4;
  for (int c = 0; c < 4; ++c) {
    __syncthreads();
#pragma unroll
    for (int t = 0; t < 4; ++t) {
      int slot = tid + t * 256;
      int half = slot >> 9, rem = slot & 511;
      const unsigned short* src = c1f + (size_t)half * 16384 + ((size_t)c * 512 + rem) * 8;
      *(bf16x8*)(&Bl[half][rem * 8]) = *(const bf16x8*)src;
    }
    __syncthreads();
    int trow = 16 * w + l15;
    int k0 = c * 32 + l4 * 8;
    float tv[8];
    *(float4*)(tv) = *(const float4*)(&T[trow][k0]);
    *(float4*)(tv + 4) = *(const float4*)(&T[trow][k0 + 4]);
    bf16x8 ah, al;
#pragma unroll
    for (int j = 0; j < 8; ++j) {
      unsigned u = __float_as_uint(tv[j]);
      ah[j] = (short)(u >> 16);
      float hi_f = __uint_as_float(u & 0xFFFF0000u);
      al[j] = (short)bf16_rn(tv[j] - hi_f);
    }
#pragma unroll
    for (int cf = 0; cf < 8; ++cf) {
      bf16x8 bh = *(const bf16x8*)(&Bl[0][cf * 512 + lane * 8]);
      bf16x8 bl = *(const bf16x8*)(&Bl[1][cf * 512 + lane * 8]);
      acc[cf] = MFMA16(ah, bh, acc[cf]);
      acc[cf] = MFMA16(al, bh, acc[cf]);
      acc[cf] = MFMA16(ah, bl, acc[cf]);
    }
  }
  // epilogue 3: cw = silu(.)·cW2 reduced over cols; cw*rel segment-sum -> coordacc
  {
    float p[4] = {0.f, 0.f, 0.f, 0.f};
#pragma unroll
    for (int cf = 0; cf < 8; ++cf) {
      int col = cf * 16 + l15;
      float bb = cb1[col];
      float w2 = cW2[col];
#pragma unroll
      for (int r = 0; r < 4; ++r) p[r] += silu_f(acc[cf][r] + bb) * w2;
    }
#pragma unroll
    for (int d = 1; d < 16; d <<= 1) {
#pragma unroll
      for (int r = 0; r < 4; ++r) p[r] += __shfl_xor(p[r], d);
    }
    // every lane now holds cw for rows 16w+l4*4+r; lane l15<3 handles comp l15
    int seg = 0;
    while (seg < 16) {
      int node = srow[16 * w + seg];
      int se = seg + 1;
      while (se < 16 && srow[16 * w + se] == node) ++se;
      float s = 0.f;
      if (l15 < 3) {
#pragma unroll
        for (int r = 0; r < 4; ++r) {
          int row = l4 * 4 + r;
          s += (row >= seg && row < se) ? p[r] * srel[16 * w + row][l15] : 0.f;
        }
      }
      s += __shfl_xor(s, 16);
      s += __shfl_xor(s, 32);
      if (l4 == 0 && l15 < 3) atomicAdd(&coordacc[(size_t)node * 4 + l15], s);
      seg = se;
    }
  }
}

// pos finalize: pos += coordacc / (deg + 1e-6)
__global__ void k_pos_fin(const float* __restrict__ coordacc, const int* __restrict__ offs,
                          float* __restrict__ pos) {
  int n = blockIdx.x * 256 + threadIdx.x;
  if (n < N_NODES) {
    float deg = (float)(offs[n + 1] - offs[n]);
    float inv = __fdividef(1.0f, deg + 1e-6f);
    pos[n * 3 + 0] += coordacc[n * 4 + 0] * inv;
    pos[n * 3 + 1] += coordacc[n * 4 + 1] * inv;
    pos[n * 3 + 2] += coordacc[n * 4 + 2] * inv;
  }
}

// ---------------------------------------------------------------------------
// Generic fp32 GEMM (injector layers 2/3 only)
// ---------------------------------------------------------------------------
template <int ACT>
__global__ __launch_bounds__(256, 2) void k_gemm128(const float* Ag, const float* __restrict__ W,
                                                    const float* __restrict__ bias, float* C, int K) {
  __shared__ float As[64][33];
  __shared__ float Ws[32][128];
  const int tid = threadIdx.x;
  const int tc = tid & 15, tr = tid >> 4;
  const int tr4 = tr * 4, tc4 = tc * 4;
  const int m0 = blockIdx.x * 64;

  float acc[4][8];
#pragma unroll
  for (int i = 0; i < 4; ++i)
#pragma unroll
    for (int j = 0; j < 8; ++j) acc[i][j] = 0.0f;

  for (int kk = 0; kk < K; kk += 32) {
    int idx = tid;
#pragma unroll
    for (int it = 0; it < 2; ++it, idx += 256) {
      int r = idx >> 3, c4 = (idx & 7) << 2;
      float4 v = *(const float4*)(Ag + (size_t)(m0 + r) * K + kk + c4);
      As[r][c4] = v.x; As[r][c4 + 1] = v.y; As[r][c4 + 2] = v.z; As[r][c4 + 3] = v.w;
    }
    idx = tid;
#pragma unroll
    for (int it = 0; it < 4; ++it, idx += 256) {
      int r = idx >> 5, c4 = (idx & 31) << 2;
      *(float4*)(&Ws[r][c4]) = *(const float4*)(W + (size_t)(kk + r) * 128 + c4);
    }
    __syncthreads();
#pragma unroll
    for (int k = 0; k < 32; ++k) {
      float av[4];
#pragma unroll
      for (int i = 0; i < 4; ++i) av[i] = As[tr4 + i][k];
      float4 b0 = *(const float4*)(&Ws[k][tc4]);
      float4 b1 = *(const float4*)(&Ws[k][64 + tc4]);
      float bv[8] = {b0.x, b0.y, b0.z, b0.w, b1.x, b1.y, b1.z, b1.w};
#pragma unroll
      for (int i = 0; i < 4; ++i)
#pragma unroll
        for (int j = 0; j < 8; ++j) acc[i][j] = fmaf(av[i], bv[j], acc[i][j]);
    }
    __syncthreads();
  }

  float bv0[8];
#pragma unroll
  for (int j = 0; j < 4; ++j) { bv0[j] = bias[tc4 + j]; bv0[4 + j] = bias[64 + tc4 + j]; }
#pragma unroll
  for (int i = 0; i < 4; ++i) {
    size_t row = m0 + tr4 + i;
    float o[8];
#pragma unroll
    for (int j = 0; j < 8; ++j) {
      float v = acc[i][j] + bv0[j];
      if (ACT >= 1) v = silu_f(v);
      o[j] = v;
    }
    *(float4*)(C + row * 128 + tc4) = make_float4(o[0], o[1], o[2], o[3]);
    *(float4*)(C + row * 128 + 64 + tc4) = make_float4(o[4], o[5], o[6], o[7]);
  }
}

// ---------------------------------------------------------------------------
// CSR build
// ---------------------------------------------------------------------------
__global__ void k_count(const int* __restrict__ rows, int* __restrict__ cnt) {
  int e = blockIdx.x * 256 + threadIdx.x;
  if (e < E_EDGES) atomicAdd(&cnt[rows[e]], 1);
}

__global__ void k_scan(const int* __restrict__ cnt, int* __restrict__ offs) {
  __shared__ int part[256];
  const int tid = threadIdx.x;
  const int base = tid * 64;
  int s = 0;
  for (int i = 0; i < 64; ++i) s += cnt[base + i];
  part[tid] = s;
  __syncthreads();
  for (int d = 1; d < 256; d <<= 1) {
    int v = (tid >= d) ? part[tid - d] : 0;
    __syncthreads();
    part[tid] += v;
    __syncthreads();
  }
  int run = part[tid] - s;
  for (int i = 0; i < 64; ++i) { offs[base + i] = run; run += cnt[base + i]; }
  if (tid == 255) offs[N_NODES] = run;
}

__global__ void k_fill(const int* __restrict__ rows, const int* __restrict__ offs,
                       int* __restrict__ fill, int* __restrict__ perm) {
  int e = blockIdx.x * 256 + threadIdx.x;
  if (e < E_EDGES) {
    int r = rows[e];
    int p = atomicAdd(&fill[r], 1);
    perm[offs[r] + p] = e;
  }
}

// ---------------------------------------------------------------------------
// Node MLP + residual + LayerNorm (fused, in-place on h)
// ---------------------------------------------------------------------------
__global__ __launch_bounds__(256, 2) void k_node_mlp(float* __restrict__ h, const float* __restrict__ agg,
                                                     const float* __restrict__ W1, const float* __restrict__ b1,
                                                     const float* __restrict__ W2, const float* __restrict__ b2,
                                                     const float* __restrict__ lng, const float* __restrict__ lnb) {
  __shared__ float As[64][33];
  __shared__ float Ws[32][128];
  __shared__ float T[64][132];
  const int tid = threadIdx.x;
  const int tc = tid & 15, tr = tid >> 4;
  const int tr4 = tr * 4, tc4 = tc * 4;
  const int m0 = blockIdx.x * 64;

  float acc[4][8];
#pragma unroll
  for (int i = 0; i < 4; ++i)
#pragma unroll
    for (int j = 0; j < 8; ++j) acc[i][j] = 0.0f;

  for (int kk = 0; kk < 256; kk += 32) {
    const float* src = (kk < 128) ? h : agg;
    const int kb = kk & 127;
    int idx = tid;
#pragma unroll
    for (int it = 0; it < 2; ++it, idx += 256) {
      int r = idx >> 3, c4 = (idx & 7) << 2;
      float4 v = *(const float4*)(src + (size_t)(m0 + r) * 128 + kb + c4);
      As[r][c4] = v.x; As[r][c4 + 1] = v.y; As[r][c4 + 2] = v.z; As[r][c4 + 3] = v.w;
    }
    idx = tid;
#pragma unroll
    for (int it = 0; it < 4; ++it, idx += 256) {
      int r = idx >> 5, c4 = (idx & 31) << 2;
      *(float4*)(&Ws[r][c4]) = *(const float4*)(W1 + (size_t)(kk + r) * 128 + c4);
    }
    __syncthreads();
#pragma unroll
    for (int k = 0; k < 32; ++k) {
      float av[4];
#pragma unroll
      for (int i = 0; i < 4; ++i) av[i] = As[tr4 + i][k];
      float4 b0 = *(const float4*)(&Ws[k][tc4]);
      float4 b1v = *(const float4*)(&Ws[k][64 + tc4]);
      float bv[8] = {b0.x, b0.y, b0.z, b0.w, b1v.x, b1v.y, b1v.z, b1v.w};
#pragma unroll
      for (int i = 0; i < 4; ++i)
#pragma unroll
        for (int j = 0; j < 8; ++j) acc[i][j] = fmaf(av[i], bv[j], acc[i][j]);
    }
    __syncthreads();
  }
#pragma unroll
  for (int i = 0; i < 4; ++i) {
#pragma unroll
    for (int j = 0; j < 4; ++j) {
      T[tr4 + i][tc4 + j] = silu_f(acc[i][j] + b1[tc4 + j]);
      T[tr4 + i][64 + tc4 + j] = silu_f(acc[i][4 + j] + b1[64 + tc4 + j]);
    }
  }
  __syncthreads();

  float acc2[4][8];
#pragma unroll
  for (int i = 0; i < 4; ++i)
#pragma unroll
    for (int j = 0; j < 8; ++j) acc2[i][j] = 0.0f;
  for (int kk = 0; kk < 128; kk += 32) {
    int idx = tid;
#pragma unroll
    for (int it = 0; it < 4; ++it, idx += 256) {
      int r = idx >> 5, c4 = (idx & 31) << 2;
      *(float4*)(&Ws[r][c4]) = *(const float4*)(W2 + (size_t)(kk + r) * 128 + c4);
    }
    __syncthreads();
#pragma unroll
    for (int k = 0; k < 32; ++k) {
      float av[4];
#pragma unroll
      for (int i = 0; i < 4; ++i) av[i] = T[tr4 + i][kk + k];
      float4 b0 = *(const float4*)(&Ws[k][tc4]);
      float4 b1v = *(const float4*)(&Ws[k][64 + tc4]);
      float bv[8] = {b0.x, b0.y, b0.z, b0.w, b1v.x, b1v.y, b1v.z, b1v.w};
#pragma unroll
      for (int i = 0; i < 4; ++i)
#pragma unroll
        for (int j = 0; j < 8; ++j) acc2[i][j] = fmaf(av[i], bv[j], acc2[i][j]);
    }
    __syncthreads();
  }

  float x[4][8], s1[4], s2[4];
#pragma unroll
  for (int i = 0; i < 4; ++i) {
    size_t row = m0 + tr4 + i;
    float4 h0 = *(const float4*)(h + row * 128 + tc4);
    float4 h1 = *(const float4*)(h + row * 128 + 64 + tc4);
    float hv[8] = {h0.x, h0.y, h0.z, h0.w, h1.x, h1.y, h1.z, h1.w};
    s1[i] = 0.f; s2[i] = 0.f;
#pragma unroll
    for (int j = 0; j < 8; ++j) {
      int cidx = (j < 4) ? (tc4 + j) : (64 + tc4 + (j - 4));
      float v = hv[j] + acc2[i][j] + b2[cidx];
      x[i][j] = v;
      s1[i] += v;
      s2[i] += v * v;
    }
  }
#pragma unroll
  for (int d = 1; d < 16; d <<= 1) {
#pragma unroll
    for (int i = 0; i < 4; ++i) {
      s1[i] += __shfl_xor(s1[i], d);
      s2[i] += __shfl_xor(s2[i], d);
    }
  }
  float gv[8], bvv[8];
#pragma unroll
  for (int j = 0; j < 4; ++j) {
    gv[j] = lng[tc4 + j]; gv[4 + j] = lng[64 + tc4 + j];
    bvv[j] = lnb[tc4 + j]; bvv[4 + j] = lnb[64 + tc4 + j];
  }
#pragma unroll
  for (int i = 0; i < 4; ++i) {
    float mu = s1[i] * (1.0f / 128.0f);
    float var = s2[i] * (1.0f / 128.0f) - mu * mu;
    float rs = rsqrtf(var + 1e-5f);
    size_t row = m0 + tr4 + i;
    float o[8];
#pragma unroll
    for (int j = 0; j < 8; ++j) o[j] = (x[i][j] - mu) * rs * gv[j] + bvv[j];
    *(float4*)(h + row * 128 + tc4) = make_float4(o[0], o[1], o[2], o[3]);
    *(float4*)(h + row * 128 + 64 + tc4) = make_float4(o[4], o[5], o[6], o[7]);
  }
}

// ---------------------------------------------------------------------------
// Injector layer 1
// ---------------------------------------------------------------------------
__global__ __launch_bounds__(256) void k_inj1(const float* __restrict__ at, const float* __restrict__ z,
                                              const float* __restrict__ W1, const float* __restrict__ b1,
                                              float* __restrict__ out) {
  __shared__ float As[64][84];
  __shared__ float Ws[80][128];
  const int tid = threadIdx.x;
  const int tc = tid & 15, tr = tid >> 4;
  const int tr4 = tr * 4, tc4 = tc * 4;
  const int m0 = blockIdx.y * 64;
  const int cb = blockIdx.x * 128;

  int idx = tid;
#pragma unroll
  for (int it = 0; it < 5; ++it, idx += 256) {
    int r = idx / 20, c4 = idx % 20;
    int n = m0 + r;
    float4 v;
    if (c4 < 4) v = *(const float4*)(at + (size_t)n * 16 + c4 * 4);
    else v = *(const float4*)(z + (size_t)(n >> 6) * 64 + (c4 - 4) * 4);
    *(float4*)(&As[r][c4 * 4]) = v;
  }
  idx = tid;
#pragma unroll
  for (int it = 0; it < 10; ++it, idx += 256) {
    int r = idx >> 5, c4 = (idx & 31) << 2;
    *(float4*)(&Ws[r][c4]) = *(const float4*)(W1 + (size_t)r * 256 + cb + c4);
  }
  __syncthreads();

  float acc[4][8];
#pragma unroll
  for (int i = 0; i < 4; ++i)
#pragma unroll
    for (int j = 0; j < 8; ++j) acc[i][j] = 0.0f;
#pragma unroll 4
  for (int k = 0; k < 80; ++k) {
    float av[4];
#pragma unroll
    for (int i = 0; i < 4; ++i) av[i] = As[tr4 + i][k];
    float4 b0 = *(const float4*)(&Ws[k][tc4]);
    float4 b1v = *(const float4*)(&Ws[k][64 + tc4]);
    float bv[8] = {b0.x, b0.y, b0.z, b0.w, b1v.x, b1v.y, b1v.z, b1v.w};
#pragma unroll
    for (int i = 0; i < 4; ++i)
#pragma unroll
      for (int j = 0; j < 8; ++j) acc[i][j] = fmaf(av[i], bv[j], acc[i][j]);
  }

  float bb[8];
#pragma unroll
  for (int j = 0; j < 4; ++j) { bb[j] = b1[cb + tc4 + j]; bb[4 + j] = b1[cb + 64 + tc4 + j]; }
#pragma unroll
  for (int i = 0; i < 4; ++i) {
    size_t row = m0 + tr4 + i;
    float o[8];
#pragma unroll
    for (int j = 0; j < 8; ++j) o[j] = silu_f(acc[i][j] + bb[j]);
    *(float4*)(out + row * 256 + cb + tc4) = make_float4(o[0], o[1], o[2], o[3]);
    *(float4*)(out + row * 256 + cb + 64 + tc4) = make_float4(o[4], o[5], o[6], o[7]);
  }
}

__global__ void k_copyf(const float* __restrict__ in, float* __restrict__ out, int n) {
  int i = blockIdx.x * 256 + threadIdx.x;
  if (i < n) out[i] = in[i];
}

// ---------------------------------------------------------------------------
extern "C" void kernel_launch(void* const* d_in, const int* in_sizes, int n_in,
                              void* d_out, int out_size, void* d_ws, size_t ws_size,
                              hipStream_t stream) {
  const float* z = (const float*)d_in[0];
  const float* at = (const float*)d_in[1];
  const float* pos0 = (const float*)d_in[2];
  const int* ei = (const int*)d_in[3];
  const float* injW1 = (const float*)d_in[4];
  const float* injb1 = (const float*)d_in[5];
  const float* injW2 = (const float*)d_in[6];
  const float* injb2 = (const float*)d_in[7];
  const float* injW3 = (const float*)d_in[8];
  const float* injb3 = (const float*)d_in[9];
  const float* eW1 = (const float*)d_in[10];
  const float* eb1 = (const float*)d_in[11];
  const float* eW2 = (const float*)d_in[12];
  const float* eb2 = (const float*)d_in[13];
  const float* cW1 = (const float*)d_in[14];
  const float* cb1 = (const float*)d_in[15];
  const float* cW2 = (const float*)d_in[16];
  const float* nW1 = (const float*)d_in[17];
  const float* nb1 = (const float*)d_in[18];
  const float* nW2 = (const float*)d_in[19];
  const float* nb2 = (const float*)d_in[20];
  const float* lng = (const float*)d_in[21];
  const float* lnb = (const float*)d_in[22];

  float* w = (float*)d_ws;
  float* h = w;        w += (size_t)N_NODES * HD;      // 2M f
  float* pos = w;      w += (size_t)N_NODES * 3;
  float* agg = w;      w += (size_t)N_NODES * HD;      // 2M f (atomic target)
  float* coordacc = w; w += (size_t)N_NODES * 4;
  float* t1 = w;       w += (size_t)N_NODES * 256;     // injector temp
  float* t2 = w;       w += (size_t)N_NODES * HD;
  unsigned short* hhi = (unsigned short*)w;            // dedicated (no alias)
  unsigned short* hlo = hhi + (size_t)N_NODES * HD;
  unsigned short* e1f = hlo + (size_t)N_NODES * HD;    // 4 * 65536
  unsigned short* e2f = e1f + (size_t)4 * 65536;       // 4 * 32768
  unsigned short* c1f = e2f + (size_t)4 * 32768;       // 4 * 32768
  int* ib = (int*)(c1f + (size_t)4 * 32768);
  int* cnt = ib;  ib += N_NODES;
  int* offs = ib; ib += N_NODES + 1;
  int* fill = ib; ib += N_NODES;
  int* perm = ib; ib += E_EDGES;

  const int* rowsp = ei;
  const int* colsp = ei + E_EDGES;

  // CSR build
  hipMemsetAsync(cnt, 0, N_NODES * sizeof(int), stream);
  hipMemsetAsync(fill, 0, N_NODES * sizeof(int), stream);
  k_count<<<E_EDGES / 256, 256, 0, stream>>>(rowsp, cnt);
  k_scan<<<1, 256, 0, stream>>>(cnt, offs);
  k_fill<<<E_EDGES / 256, 256, 0, stream>>>(rowsp, offs, fill, perm);
  k_copyf<<<(N_NODES * 3 + 255) / 256, 256, 0, stream>>>(pos0, pos, N_NODES * 3);

  // weight prep (frag-linear bf16 hi/lo)
  k_prep_w<<<128, 256, 0, stream>>>(eW1, eW2, cW1, e1f, e2f, c1f);

  // latent injection
  k_inj1<<<dim3(2, N_NODES / 64), 256, 0, stream>>>(at, z, injW1, injb1, t1);
  k_gemm128<1><<<N_NODES / 64, 256, 0, stream>>>(t1, injW2, injb2, t2, 256);
  k_gemm128<0><<<N_NODES / 64, 256, 0, stream>>>(t2, injW3, injb3, h, 128);

  for (int l = 0; l < NLAYER; ++l) {
    hipMemsetAsync(agg, 0, (size_t)N_NODES * HD * sizeof(float), stream);
    hipMemsetAsync(coordacc, 0, (size_t)N_NODES * 4 * sizeof(float), stream);
    k_h2bf<<<(N_NODES * HD / 8) / 256, 256, 0, stream>>>(h, hhi, hlo);
    k_edge_mfma<<<E_EDGES / 64, 256, 0, stream>>>(
        hhi, hlo, pos, rowsp, colsp, perm,
        e1f + (size_t)l * 65536, eW1 + (size_t)l * 257 * HD, eb1 + l * HD,
        e2f + (size_t)l * 32768, eb2 + l * HD,
        c1f + (size_t)l * 32768, cb1 + l * HD,
        cW2 + (size_t)l * HD,
        agg, coordacc);
    k_pos_fin<<<N_NODES / 256, 256, 0, stream>>>(coordacc, offs, pos);
    k_node_mlp<<<N_NODES / 64, 256, 0, stream>>>(h, agg, nW1 + (size_t)l * 2 * HD * HD, nb1 + l * HD,
                                                 nW2 + (size_t)l * HD * HD, nb2 + l * HD,
                                                 lng + l * HD, lnb + l * HD);
  }
  k_copyf<<<(N_NODES * 3 + 255) / 256, 256, 0, stream>>>(pos, (float*)d_out, N_NODES * 3);
}